// Round 8
// baseline (509.079 us; speedup 1.0000x reference)
//
#include <hip/hip_runtime.h>
#include <math.h>

#define BB   32
#define CC   256
#define DD   256
#define KK   4096
#define HW   1024
#define NPIX 32768   // B*H*W
#define NELE 8388608 // B*D*H*W
#define EPS_REPAIR 1e-6f

typedef unsigned short ushort_t;
typedef __attribute__((ext_vector_type(8))) short short8;
typedef __attribute__((ext_vector_type(4))) float f32x4;

__device__ __forceinline__ unsigned short f2bf(float v) {
    union { float f; unsigned u; } c; c.f = v;
    unsigned r = c.u + 0x7FFFu + ((c.u >> 16) & 1u);  // RN-even
    return (unsigned short)(r >> 16);
}
__device__ __forceinline__ float bf2f(unsigned short b) {
    union { unsigned u; float f; } c; c.u = ((unsigned)b) << 16;
    return c.f;
}
__device__ __forceinline__ void gll16(const void* g, void* l) {
    __builtin_amdgcn_global_load_lds(
        (const __attribute__((address_space(1))) void*)g,
        (__attribute__((address_space(3))) void*)l, 16, 0, 0);
}

// ---------------- K1: pack emb -> Bp=[bh|bh|bl] bf16, e_norm; fused zeroing ----------------
__global__ void k_packB(const float* __restrict__ emb, ushort_t* __restrict__ Bp,
                        float* __restrict__ e_norm, int* __restrict__ counts,
                        float* __restrict__ accum) {
    int k = blockIdx.x;
    int lane = threadIdx.x; // 64
    if (lane == 0) counts[k] = 0;
    if (k == 0 && lane < 2) accum[lane] = 0.0f;
    float4 v = reinterpret_cast<const float4*>(emb + (size_t)k * DD)[lane];
    float s = v.x * v.x + v.y * v.y + v.z * v.z + v.w * v.w;
    float vv[4] = {v.x, v.y, v.z, v.w};
    ushort_t* row = Bp + (size_t)k * 768 + lane * 4;
    #pragma unroll
    for (int c = 0; c < 4; ++c) {
        unsigned short h = f2bf(vv[c]);
        unsigned short l = f2bf(vv[c] - bf2f(h));
        row[c] = h; row[256 + c] = h; row[512 + c] = l;
    }
    #pragma unroll
    for (int off = 32; off; off >>= 1) s += __shfl_down(s, off);
    if (lane == 0) e_norm[k] = s;
}

// ---------------- K2: 1x1 conv -> A2=[zh|zl] bf16 pairs [N][512]; accumulates sum(||z||^2) ----------------
__global__ __launch_bounds__(256) void k_conv(const float* __restrict__ x,
                                              const float* __restrict__ w,
                                              const float* __restrict__ bias,
                                              ushort_t* __restrict__ A2,
                                              float* __restrict__ accum) {
    __shared__ __align__(16) float xt[32][260];
    int t = threadIdx.x;
    int n0 = blockIdx.x * 32;
    int b = n0 >> 10, hw0 = n0 & 1023;
    const float* xb = x + (size_t)b * (CC * HW) + hw0;

    int p = t & 31, cg = t >> 5;
    #pragma unroll
    for (int it = 0; it < 32; ++it) {
        int c = it * 8 + cg;
        xt[p][c] = xb[c * HW + p];
    }
    __syncthreads();

    int d = t;
    float acc[32];
    float bv = bias[d];
    #pragma unroll
    for (int i = 0; i < 32; ++i) acc[i] = bv;

    const float4* wrow = reinterpret_cast<const float4*>(w + (size_t)d * CC);
    for (int c4 = 0; c4 < 64; ++c4) {
        float4 w4 = wrow[c4];
        #pragma unroll
        for (int pp = 0; pp < 32; ++pp) {
            float4 x4 = *reinterpret_cast<const float4*>(&xt[pp][c4 * 4]);
            acc[pp] = fmaf(w4.x, x4.x, acc[pp]);
            acc[pp] = fmaf(w4.y, x4.y, acc[pp]);
            acc[pp] = fmaf(w4.z, x4.z, acc[pp]);
            acc[pp] = fmaf(w4.w, x4.w, acc[pp]);
        }
    }
    float zs = 0.0f;
    #pragma unroll
    for (int pp = 0; pp < 32; ++pp) {
        float v = acc[pp];
        zs = fmaf(v, v, zs);
        unsigned short h = f2bf(v);
        unsigned short l = f2bf(v - bf2f(h));
        ushort_t* arow = A2 + (size_t)(n0 + pp) * 512;
        arow[d] = h; arow[256 + d] = l;
    }
    // block-reduce sum(z^2) -> accum[0]
    #pragma unroll
    for (int off = 32; off; off >>= 1) zs += __shfl_down(zs, off);
    __shared__ float wsum[4];
    if ((t & 63) == 0) wsum[t >> 6] = zs;
    __syncthreads();
    if (t == 0) atomicAdd(accum, wsum[0] + wsum[1] + wsum[2] + wsum[3]);
}

// ---------------- K3: MFMA GEMM + per-pixel top2 over codes ----------------
// 256x128 tiles, 8 waves (4 row x 2 col, 64x64 each), BK=64, THREE LDS buffers,
// depth-2 prefetch with counted s_waitcnt vmcnt(6) (never 0 in steady state).
// STAGING IS LANE-LINEAR (global_load_lds writes base+lane*16: thread t's LDS
// dest byte offset == t*16 + s*8192 -- R7 bug was a non-lane-linear pattern).
// lgkmcnt(0) before each s_barrier (all my ds_reads sampled before anyone
// overwrites that buffer); sched_barrier(0) after s_barrier (raw s_barrier is
// not a compiler fence -- pins ds_reads below it).
// XOR-swizzled LDS (linear dest + pre-swizzled global src + swizzled read).
// XCD-aware: 2 XCDs per 1024-code chunk (B-chunk 1.57 MB L2-resident).
__global__ __launch_bounds__(512, 2) void k_mfma_top2(
    const ushort_t* __restrict__ A2,   // [NPIX][512]  = [zh|zl]
    const ushort_t* __restrict__ Bp,   // [KK][768]    = [bh|bh|bl]
    const float* __restrict__ e_norm,
    float* __restrict__ tv1, int* __restrict__ ti1,
    float* __restrict__ tv2, int* __restrict__ ti2) {
    __shared__ __align__(16) short As[3][256][64];  // 96 KB
    __shared__ __align__(16) short Bs[3][128][64];  // 48 KB
    __shared__ float en_lds[1024];                  //  4 KB

    const int t = threadIdx.x;
    const int xcd = blockIdx.x & 7, slot = blockIdx.x >> 3;
    const int ch = xcd >> 1;                        // 0..3 code chunk
    const int mb = ((xcd & 1) << 6) | slot;         // 0..127 m-tile
    const int n0 = mb * 256, c0 = ch * 1024;
    const int w = t >> 6, lane = t & 63;
    const int wr = w >> 1, wc = w & 1;              // 4x2 wave grid
    const int lr = lane & 15, lg = lane >> 4;

    // staging coords: thread t covers granule (t&7) of rows (t>>3)+64*s
    // -> LDS byte offset t*16 + s*8192 (lane-linear, required by gll16)
    const int sg   = t & 7;        // granule slot in LDS row
    const int srow = t >> 3;       // base row (+64*s)

    auto stage = [&](int buf, int sub_, int ks_) {
        const int Acol = ((ks_ < 8) ? ks_ : ks_ - 8) * 64;  // A'=[zh|zl|zh]
        const int Bcol = ks_ * 64;
        const int q = (sg ^ (srow & 7)) << 3;  // pre-swizzled global col (shorts)
        #pragma unroll
        for (int s = 0; s < 4; ++s) {
            const int r = srow + 64 * s;       // (r&7)==(srow&7)
            gll16(&A2[(size_t)(n0 + r) * 512 + Acol + q], &As[buf][r][sg << 3]);
        }
        #pragma unroll
        for (int s = 0; s < 2; ++s) {
            const int r = srow + 64 * s;
            gll16(&Bp[(size_t)(c0 + sub_ * 128 + r) * 768 + Bcol + q], &Bs[buf][r][sg << 3]);
        }
    };

    float v1[4][4], v2r[4][4];
    int   i1[4][4], i2r[4][4];
    #pragma unroll
    for (int m = 0; m < 4; ++m)
        #pragma unroll
        for (int j = 0; j < 4; ++j) {
            v1[m][j] = 3.0e38f; v2r[m][j] = 3.0e38f;
            i1[m][j] = 0x7FFFFFFF; i2r[m][j] = 0x7FFFFFFF;
        }

    // prologue: e_norm chunk -> LDS (lane-linear: byte offset t*16); stage batches 0,1
    if (t < 256) gll16(&e_norm[c0 + t * 4], &en_lds[t * 4]);
    stage(0, 0, 0);
    stage(1, 0, 1);

    f32x4 acc[4][4];
    for (int sub = 0; sub < 8; ++sub) {
        #pragma unroll
        for (int ks = 0; ks < 12; ++ks) {
            // batch i landed; one batch (6 loads) stays in flight.
            if (ks == 11 && sub == 7) { asm volatile("s_waitcnt vmcnt(0) lgkmcnt(0)" ::: "memory"); }
            else                      { asm volatile("s_waitcnt vmcnt(6) lgkmcnt(0)" ::: "memory"); }
            __builtin_amdgcn_s_barrier();
            __builtin_amdgcn_sched_barrier(0);   // nothing crosses the barrier

            // issue stage(i+2) into buf (i+2)%3 (its last reader finished at iter i-1)
            if (ks + 2 < 12) {
                stage((ks + 2) % 3, sub, ks + 2);
            } else if (sub < 7) {
                stage((ks + 2) % 3, sub + 1, ks + 2 - 12);
            }

            if (ks == 0) {
                const f32x4 vz = {0.f, 0.f, 0.f, 0.f};
                #pragma unroll
                for (int m = 0; m < 4; ++m)
                    #pragma unroll
                    for (int n = 0; n < 4; ++n) acc[m][n] = vz;
            }
            const int buf = ks % 3;
            #pragma unroll
            for (int kk = 0; kk < 2; ++kk) {
                short8 a[4], b[4];
                #pragma unroll
                for (int m = 0; m < 4; ++m) {
                    const int r = wr * 64 + m * 16 + lr;
                    a[m] = *reinterpret_cast<const short8*>(
                        &As[buf][r][((kk * 4 + lg) ^ (r & 7)) << 3]);
                }
                #pragma unroll
                for (int n = 0; n < 4; ++n) {
                    const int r = wc * 64 + n * 16 + lr;
                    b[n] = *reinterpret_cast<const short8*>(
                        &Bs[buf][r][((kk * 4 + lg) ^ (r & 7)) << 3]);
                }
                #pragma unroll
                for (int m = 0; m < 4; ++m)
                    #pragma unroll
                    for (int n = 0; n < 4; ++n)
                        acc[m][n] = __builtin_amdgcn_mfma_f32_16x16x32_bf16(
                            a[m], b[n], acc[m][n], 0, 0, 0);
            }
            if (ks == 11) {  // fold 128-code sub-tile into running top2
                const int base = sub * 128 + wc * 64;
                #pragma unroll
                for (int n = 0; n < 4; ++n) {
                    const float en = en_lds[base + n * 16 + lr];
                    const int col = c0 + base + n * 16 + lr;
                    #pragma unroll
                    for (int m = 0; m < 4; ++m)
                        #pragma unroll
                        for (int j = 0; j < 4; ++j) {
                            const float s = fmaf(-2.0f, acc[m][n][j], en);
                            const bool b1 = s < v1[m][j];
                            const bool b2 = s < v2r[m][j];
                            v2r[m][j] = b1 ? v1[m][j] : (b2 ? s : v2r[m][j]);
                            i2r[m][j] = b1 ? i1[m][j] : (b2 ? col : i2r[m][j]);
                            v1[m][j]  = b1 ? s   : v1[m][j];
                            i1[m][j]  = b1 ? col : i1[m][j];
                        }
                }
            }
        }
    }

    // cross-lane top2 merge across the 16 lanes sharing each row
    #pragma unroll
    for (int mask = 1; mask <= 8; mask <<= 1) {
        #pragma unroll
        for (int m = 0; m < 4; ++m)
            #pragma unroll
            for (int j = 0; j < 4; ++j) {
                const float ov1 = __shfl_xor(v1[m][j], mask);
                const int   oi1 = __shfl_xor(i1[m][j], mask);
                const float ov2 = __shfl_xor(v2r[m][j], mask);
                const int   oi2 = __shfl_xor(i2r[m][j], mask);
                const bool tb = (ov1 < v1[m][j]) || (ov1 == v1[m][j] && oi1 < i1[m][j]);
                const float w1 = tb ? ov1 : v1[m][j];  const int w1i = tb ? oi1 : i1[m][j];
                const float l1 = tb ? v1[m][j] : ov1;  const int l1i = tb ? i1[m][j] : oi1;
                const float c2 = tb ? ov2 : v2r[m][j]; const int c2i = tb ? oi2 : i2r[m][j];
                const bool t2b = (c2 < l1) || (c2 == l1 && c2i < l1i);
                v1[m][j] = w1; i1[m][j] = w1i;
                v2r[m][j] = t2b ? c2 : l1; i2r[m][j] = t2b ? c2i : l1i;
            }
    }
    __syncthreads();  // all LDS tile reads done; safe to alias merge scratch
    float* mgv = (float*)&As[0][0][0];                     // [256][2][2] floats (4 KB)
    int*   mgi = (int*)((char*)&As[0][0][0] + 4096);       // [256][2][2] ints  (4 KB)
    if (lr == 0) {
        #pragma unroll
        for (int m = 0; m < 4; ++m)
            #pragma unroll
            for (int j = 0; j < 4; ++j) {
                const int r = wr * 64 + m * 16 + lg * 4 + j;
                mgv[(r * 2 + wc) * 2 + 0] = v1[m][j];  mgv[(r * 2 + wc) * 2 + 1] = v2r[m][j];
                mgi[(r * 2 + wc) * 2 + 0] = i1[m][j];  mgi[(r * 2 + wc) * 2 + 1] = i2r[m][j];
            }
    }
    __syncthreads();
    if (t < 256) {
        const float a1 = mgv[(t * 2 + 0) * 2 + 0], a2 = mgv[(t * 2 + 0) * 2 + 1];
        const int  ai1 = mgi[(t * 2 + 0) * 2 + 0], ai2 = mgi[(t * 2 + 0) * 2 + 1];
        const float b1 = mgv[(t * 2 + 1) * 2 + 0], b2 = mgv[(t * 2 + 1) * 2 + 1];
        const int  bi1 = mgi[(t * 2 + 1) * 2 + 0], bi2 = mgi[(t * 2 + 1) * 2 + 1];
        const bool tb = (b1 < a1) || (b1 == a1 && bi1 < ai1);
        const float w1 = tb ? b1 : a1;  const int w1i = tb ? bi1 : ai1;
        const float l1 = tb ? a1 : b1;  const int l1i = tb ? ai1 : bi1;
        const float c2 = tb ? b2 : a2;  const int c2i = tb ? bi2 : ai2;
        const bool t2b = (c2 < l1) || (c2 == l1 && c2i < l1i);
        const size_t o = (size_t)ch * NPIX + n0 + t;
        tv1[o] = w1; ti1[o] = w1i;
        tv2[o] = t2b ? c2 : l1; ti2[o] = t2b ? c2i : l1i;
    }
}

// ---------------- K4: merge 4 chunk-top2s, exact repair of near-ties,
//                      histogram + sum(s_best) for the loss ----------------
__global__ __launch_bounds__(256) void k_select(
    const float* __restrict__ tv1, const int* __restrict__ ti1,
    const float* __restrict__ tv2, const int* __restrict__ ti2,
    const ushort_t* __restrict__ A2, const float* __restrict__ emb,
    const float* __restrict__ e_norm, int* __restrict__ idx,
    int* __restrict__ counts, float* __restrict__ accum) {
    const int t = threadIdx.x;
    const int n = blockIdx.x * 256 + t;
    float g1 = tv1[n], g2 = tv2[n];
    int  gi1 = ti1[n], gi2 = ti2[n];
    #pragma unroll
    for (int c = 1; c < 4; ++c) {
        const size_t o = (size_t)c * NPIX + n;
        const float b1 = tv1[o], b2 = tv2[o];
        const int  bi1 = ti1[o], bi2 = ti2[o];
        const bool tb = (b1 < g1) || (b1 == g1 && bi1 < gi1);
        const float w1 = tb ? b1 : g1;  const int w1i = tb ? bi1 : gi1;
        const float l1 = tb ? g1 : b1;  const int l1i = tb ? gi1 : bi1;
        const float c2 = tb ? b2 : g2;  const int c2i = tb ? bi2 : gi2;
        const bool t2b = (c2 < l1) || (c2 == l1 && c2i < l1i);
        g1 = w1; gi1 = w1i;
        g2 = t2b ? c2 : l1; gi2 = t2b ? c2i : l1i;
    }
    int best = gi1;
    float sbest = g1;
    if (g2 - g1 < EPS_REPAIR) {  // exact fp32 re-rank of the two candidates
        const ushort_t* za = A2 + (size_t)n * 512;
        const float4* e1 = reinterpret_cast<const float4*>(emb + (size_t)gi1 * DD);
        const float4* e2 = reinterpret_cast<const float4*>(emb + (size_t)gi2 * DD);
        float d1 = 0.f, d2 = 0.f;
        for (int q = 0; q < 64; ++q) {
            const float4 a1 = e1[q], a2 = e2[q];
            #pragma unroll
            for (int c = 0; c < 4; ++c) {
                const int d = q * 4 + c;
                const float z = bf2f(za[d]) + bf2f(za[256 + d]);
                const float ev1 = (&a1.x)[c], ev2 = (&a2.x)[c];
                d1 = fmaf(z, ev1, d1);
                d2 = fmaf(z, ev2, d2);
            }
        }
        const float s1 = e_norm[gi1] - 2.f * d1;
        const float s2 = e_norm[gi2] - 2.f * d2;
        const bool take2 = (s2 < s1 || (s2 == s1 && gi2 < gi1));
        best  = take2 ? gi2 : gi1;
        sbest = take2 ? s2 : s1;
    }
    idx[n] = best;
    atomicAdd(&counts[best], 1);
    // loss term: ||z-q||^2 = ||z||^2 + s_best  ->  accumulate s_best into accum[1]
    #pragma unroll
    for (int off = 32; off; off >>= 1) sbest += __shfl_down(sbest, off);
    __shared__ float wsum[4];
    if ((t & 63) == 0) wsum[t >> 6] = sbest;
    __syncthreads();
    if (t == 0) atomicAdd(accum + 1, wsum[0] + wsum[1] + wsum[2] + wsum[3]);
}

// ---------------- K5: gather emb[idx] -> out[B,D,H,W] ----------------
__global__ __launch_bounds__(256) void k_gather(const float* __restrict__ emb,
                                                const int* __restrict__ idx,
                                                float* __restrict__ out) {
    __shared__ float qt[256][33];
    int t = threadIdx.x;
    int n0 = blockIdx.x * 32;
    int b = n0 >> 10, hw0 = n0 & 1023;

    for (int p = 0; p < 32; ++p) {
        int row = idx[n0 + p];
        qt[t][p] = emb[(size_t)row * DD + t];
    }
    __syncthreads();

    int dg = t >> 5, p = t & 31;
    float* ob = out + (size_t)b * (DD * HW) + hw0;
    #pragma unroll
    for (int s = 0; s < 32; ++s) {
        int d = dg + 8 * s;
        ob[d * HW + p] = qt[d][p];
    }
}

// ---------------- K6: finalize loss + perplexity ----------------
__global__ void k_final(const int* __restrict__ counts, const float* __restrict__ accum,
                        float* __restrict__ out_scalars) {
    int t = threadIdx.x; // 256
    float s = 0.0f;
    #pragma unroll
    for (int q = 0; q < 16; ++q) {
        float p = (float)counts[t * 16 + q] * (1.0f / 32768.0f);
        s += p * logf(p + 1e-10f);
    }
    #pragma unroll
    for (int off = 32; off; off >>= 1) s += __shfl_down(s, off);
    __shared__ float wsum[4];
    if ((t & 63) == 0) wsum[t >> 6] = s;
    __syncthreads();
    if (t == 0) {
        float ent = wsum[0] + wsum[1] + wsum[2] + wsum[3];
        out_scalars[0] = (accum[0] + accum[1]) * (1.25f / (float)NELE);
        out_scalars[1] = expf(-ent);
    }
}

extern "C" void kernel_launch(void* const* d_in, const int* in_sizes, int n_in,
                              void* d_out, int out_size, void* d_ws, size_t ws_size,
                              hipStream_t stream) {
    const float* x    = (const float*)d_in[0];
    const float* w    = (const float*)d_in[1];
    const float* bias = (const float*)d_in[2];
    const float* emb  = (const float*)d_in[3];
    float* out = (float*)d_out;

    char* ws = (char*)d_ws;
    ushort_t* A2   = (ushort_t*)ws;                      // 33,554,432 B
    ushort_t* Bp   = (ushort_t*)(ws + 33554432);         //  6,291,456 B
    float* e_norm  = (float*)(ws + 39845888);            //     16,384 B
    int*   idx     = (int*)  (ws + 39862272);            //    131,072 B
    int*   counts  = (int*)  (ws + 39993344);            //     16,384 B
    float* accum   = (float*)(ws + 40009728);            //        256 B
    float* tv1     = (float*)(ws + 40009984);            //    524,288 B
    int*   ti1     = (int*)  (ws + 40534272);            //    524,288 B
    float* tv2     = (float*)(ws + 41058560);            //    524,288 B
    int*   ti2     = (int*)  (ws + 41582848);            //    524,288 B

    k_packB    <<<KK,    64, 0, stream>>>(emb, Bp, e_norm, counts, accum);
    k_conv     <<<1024, 256, 0, stream>>>(x, w, bias, A2, accum);
    k_mfma_top2<<<512,  512, 0, stream>>>(A2, Bp, e_norm, tv1, ti1, tv2, ti2);
    k_select   <<<128,  256, 0, stream>>>(tv1, ti1, tv2, ti2, A2, emb, e_norm, idx, counts, accum);
    k_gather   <<<1024, 256, 0, stream>>>(emb, idx, out);
    k_final    <<<1,    256, 0, stream>>>(counts, accum, out + NELE);
}